// Round 16
// baseline (282.376 us; speedup 1.0000x reference)
//
#include <hip/hip_runtime.h>
#include <math.h>

#define NS   768
#define DIM  512
#define NH   8
#define HD   64
#define BD   40
#define HBD  320
#define NROWS (768*768)
#define OSTRIDE 321
#define QKV_BLKS 288

typedef __bf16 bf16x8 __attribute__((ext_vector_type(8)));
typedef float  f32x4  __attribute__((ext_vector_type(4)));

union FragU {
    bf16x8 v;
    unsigned short u[8];
    uint2 d2[2];
};

__device__ inline unsigned short f2bf(float f) {
    unsigned int u = __float_as_uint(f);
    unsigned int r = (u + 0x7fffu + ((u >> 16) & 1u)) >> 16;
    return (unsigned short)r;
}
__device__ inline unsigned int pk2(float x, float y) {
    return (unsigned)f2bf(x) | ((unsigned)f2bf(y) << 16);
}

// ---------------------------------------------------------------------------
// Standalone MFMA GEMM (256 thr). Used for o1 (mode 3) / o2 (mode 0).
// mode 0: f32 row-major   1: bf16 row-major   2: bf16 col-major   3: f32+mish
// ---------------------------------------------------------------------------
__global__ __launch_bounds__(256) void gemm_mfma(const float* __restrict__ A,
                                                 const float* __restrict__ W,
                                                 const float* __restrict__ bvec,
                                                 void* __restrict__ Cout,
                                                 int mode)
{
    __shared__ unsigned short As[64][72];
    __shared__ unsigned short Ws[64][72];

    const int t   = threadIdx.x;
    const int w   = t >> 6;
    const int l   = t & 63;
    const int c16 = l & 15;
    const int g   = l >> 4;
    const int m0  = blockIdx.x * 64;
    const int cb  = blockIdx.y * 64;

    f32x4 acc[4];
#pragma unroll
    for (int tl = 0; tl < 4; ++tl) acc[tl] = (f32x4){0.f, 0.f, 0.f, 0.f};

    for (int kc = 0; kc < DIM; kc += 64) {
        __syncthreads();
#pragma unroll
        for (int rep = 0; rep < 4; ++rep) {
            int f   = t + rep * 256;
            int row = f >> 4;
            int kk  = (f & 15) << 2;
            float4 a4 = *(const float4*)&A[(size_t)(m0 + row) * DIM + kc + kk];
            *(uint2*)&As[row][kk] = make_uint2(pk2(a4.x, a4.y), pk2(a4.z, a4.w));
            float4 w4 = *(const float4*)&W[(size_t)(cb + row) * DIM + kc + kk];
            *(uint2*)&Ws[row][kk] = make_uint2(pk2(w4.x, w4.y), pk2(w4.z, w4.w));
        }
        __syncthreads();
#pragma unroll
        for (int ks = 0; ks < 2; ++ks) {
            const int k0 = ks * 32;
            FragU bA;
            bA.d2[0] = *(const uint2*)&As[w * 16 + c16][k0 + 4 * g];
            bA.d2[1] = *(const uint2*)&As[w * 16 + c16][k0 + 16 + 4 * g];
#pragma unroll
            for (int tl = 0; tl < 4; ++tl) {
                FragU aW;
                aW.d2[0] = *(const uint2*)&Ws[tl * 16 + c16][k0 + 4 * g];
                aW.d2[1] = *(const uint2*)&Ws[tl * 16 + c16][k0 + 16 + 4 * g];
                acc[tl] = __builtin_amdgcn_mfma_f32_16x16x32_bf16(aW.v, bA.v, acc[tl], 0, 0, 0);
            }
        }
    }

    const int row = m0 + w * 16 + c16;
#pragma unroll
    for (int tl = 0; tl < 4; ++tl) {
        const int col = cb + tl * 16 + g * 4;
        float4 bb = *(const float4*)&bvec[col];
        float o[4] = {acc[tl][0] + bb.x, acc[tl][1] + bb.y,
                      acc[tl][2] + bb.z, acc[tl][3] + bb.w};
        if (mode == 3) {
#pragma unroll
            for (int rr = 0; rr < 4; ++rr)
                o[rr] = o[rr] * tanhf(log1pf(expf(o[rr])));
        }
        if (mode == 0 || mode == 3) {
            *(float4*)&((float*)Cout)[(size_t)row * DIM + col] =
                make_float4(o[0], o[1], o[2], o[3]);
        } else if (mode == 1) {
            *(uint2*)&((unsigned short*)Cout)[(size_t)row * DIM + col] =
                make_uint2(pk2(o[0], o[1]), pk2(o[2], o[3]));
        } else {
            unsigned short* p = (unsigned short*)Cout;
#pragma unroll
            for (int rr = 0; rr < 4; ++rr)
                p[(size_t)(col + rr) * NS + row] = f2bf(o[rr]);
        }
    }
}

// ---------------------------------------------------------------------------
// Fused QKV + biasp, 512 threads, heterogeneous grid.
// biasp: VGPR-trimmed (no o[] array; bias-add recomputed from L1-hot bp_b),
// launch_bounds(512,6) -> 3 blocks/CU (LDS 46.1KB, VGPR <= 85).
// ---------------------------------------------------------------------------
struct SMemG { unsigned short As[64][72]; unsigned short Ws[64][72]; };
struct SMemB { unsigned short Wl[HBD * BD]; float Ostage[16 * OSTRIDE]; };
union SMemU { SMemG g; SMemB b; };

__global__ __launch_bounds__(512, 6) void qkv_biasp(
    const float* __restrict__ q, const float* __restrict__ k, const float* __restrict__ v,
    const float* __restrict__ q_w, const float* __restrict__ k_w, const float* __restrict__ v_w,
    const float* __restrict__ q_b, const float* __restrict__ k_b, const float* __restrict__ v_b,
    unsigned short* __restrict__ Qb, unsigned short* __restrict__ Kb, unsigned short* __restrict__ Vt,
    const float* __restrict__ bias, const float* __restrict__ bp_w, const float* __restrict__ bp_b,
    float* __restrict__ bias_p, float* __restrict__ diffs)
{
    __shared__ SMemU sm;

    const int t   = threadIdx.x;
    const int wv  = t >> 6;
    const int l   = t & 63;
    const int c16 = l & 15;
    const int g   = l >> 4;

    if (blockIdx.x < QKV_BLKS) {
        // ================= QKV gemm path =================
        const int sub   = blockIdx.x;
        const int which = sub / 96;            // 0=Q 1=K 2=V
        const int rem   = sub - which * 96;
        const int m0    = (rem % 12) * 64;
        const int cb    = (rem / 12) * 64;
        const float* A  = (which == 0) ? q   : (which == 1) ? k   : v;
        const float* W  = (which == 0) ? q_w : (which == 1) ? k_w : v_w;
        const float* Bv = (which == 0) ? q_b : (which == 1) ? k_b : v_b;

        const int wr = wv >> 1;
        const int wc = wv & 1;

        f32x4 acc[2];
        acc[0] = (f32x4){0.f, 0.f, 0.f, 0.f};
        acc[1] = (f32x4){0.f, 0.f, 0.f, 0.f};

        for (int kc = 0; kc < DIM; kc += 64) {
            __syncthreads();
#pragma unroll
            for (int rep = 0; rep < 2; ++rep) {
                int f   = t + rep * 512;
                int row = f >> 4;
                int kk  = (f & 15) << 2;
                float4 a4 = *(const float4*)&A[(size_t)(m0 + row) * DIM + kc + kk];
                *(uint2*)&sm.g.As[row][kk] = make_uint2(pk2(a4.x, a4.y), pk2(a4.z, a4.w));
                float4 w4 = *(const float4*)&W[(size_t)(cb + row) * DIM + kc + kk];
                *(uint2*)&sm.g.Ws[row][kk] = make_uint2(pk2(w4.x, w4.y), pk2(w4.z, w4.w));
            }
            __syncthreads();
#pragma unroll
            for (int ks = 0; ks < 2; ++ks) {
                const int k0 = ks * 32;
                FragU bA;
                bA.d2[0] = *(const uint2*)&sm.g.As[wr * 16 + c16][k0 + 4 * g];
                bA.d2[1] = *(const uint2*)&sm.g.As[wr * 16 + c16][k0 + 16 + 4 * g];
#pragma unroll
                for (int tl = 0; tl < 2; ++tl) {
                    FragU aW;
                    aW.d2[0] = *(const uint2*)&sm.g.Ws[wc * 32 + tl * 16 + c16][k0 + 4 * g];
                    aW.d2[1] = *(const uint2*)&sm.g.Ws[wc * 32 + tl * 16 + c16][k0 + 16 + 4 * g];
                    acc[tl] = __builtin_amdgcn_mfma_f32_16x16x32_bf16(aW.v, bA.v, acc[tl], 0, 0, 0);
                }
            }
        }

        const int row = m0 + wr * 16 + c16;
#pragma unroll
        for (int tl = 0; tl < 2; ++tl) {
            const int col = cb + wc * 32 + tl * 16 + g * 4;
            float4 bb = *(const float4*)&Bv[col];
            float o0 = acc[tl][0] + bb.x;
            float o1 = acc[tl][1] + bb.y;
            float o2 = acc[tl][2] + bb.z;
            float o3 = acc[tl][3] + bb.w;
            if (which < 2) {
                unsigned short* p = (which == 0) ? Qb : Kb;
                *(uint2*)&p[(size_t)row * DIM + col] =
                    make_uint2(pk2(o0, o1), pk2(o2, o3));
            } else {
                Vt[(size_t)(col + 0) * NS + row] = f2bf(o0);
                Vt[(size_t)(col + 1) * NS + row] = f2bf(o1);
                Vt[(size_t)(col + 2) * NS + row] = f2bf(o2);
                Vt[(size_t)(col + 3) * NS + row] = f2bf(o3);
            }
        }
        return;
    }

    // ================= biasp path (true 3 blocks/CU) =================
    const long row0 = (long)(blockIdx.x - QKV_BLKS) * 64;
    const int  w    = wv;
    const int  wrow = (w >> 1) * 16;
    const int  wcol = (w & 1) * 160;

    const long arow = row0 + wrow + c16;
    const float* ap = bias + arow * BD;
    float4 a0 = *(const float4*)(ap + g * 4);
    float4 a1 = *(const float4*)(ap + 16 + g * 4);
    float4 a2 = make_float4(0.f, 0.f, 0.f, 0.f);
    if (g < 2) a2 = *(const float4*)(ap + 32 + g * 4);

    for (int i = t; i < HBD * BD / 4; i += 512) {
        float4 w4 = ((const float4*)bp_w)[i];
        ((uint2*)sm.b.Wl)[i] = make_uint2(pk2(w4.x, w4.y), pk2(w4.z, w4.w));
    }

    FragU A0, A1;
    A0.d2[0] = make_uint2(pk2(a0.x, a0.y), pk2(a0.z, a0.w));
    A0.d2[1] = make_uint2(pk2(a1.x, a1.y), pk2(a1.z, a1.w));
    A1.d2[0] = make_uint2(pk2(a2.x, a2.y), pk2(a2.z, a2.w));
    A1.d2[1] = make_uint2(0u, 0u);

    __syncthreads();

    f32x4 acc[10];
#pragma unroll
    for (int tl = 0; tl < 10; ++tl) acc[tl] = (f32x4){0.f, 0.f, 0.f, 0.f};

#pragma unroll
    for (int tl = 0; tl < 10; ++tl) {
        const int n = wcol + tl * 16 + c16;
        const uint2* wp = (const uint2*)(sm.b.Wl + n * BD);
        FragU B0, B1;
        B0.d2[0] = wp[g];
        B0.d2[1] = wp[4 + g];
        B1.d2[0] = (g < 2) ? wp[8 + g] : make_uint2(0u, 0u);
        B1.d2[1] = make_uint2(0u, 0u);
        acc[tl] = __builtin_amdgcn_mfma_f32_16x16x32_bf16(B0.v, A0.v, acc[tl], 0, 0, 0);
        acc[tl] = __builtin_amdgcn_mfma_f32_16x16x32_bf16(B1.v, A1.v, acc[tl], 0, 0, 0);
    }

    // diffs epilogue: ssq from acc + bp_b on the fly (no persistent o[])
    const long brow = row0 + wrow + c16;
    {
        float ssq[4] = {0.f, 0.f, 0.f, 0.f};
#pragma unroll
        for (int tl = 0; tl < 10; ++tl) {
            const int cbase = tl * 16 + g * 4;
            float4 bb = *(const float4*)&bp_b[wcol + cbase];
            float x0 = acc[tl][0] + bb.x;
            float x1 = acc[tl][1] + bb.y;
            float x2 = acc[tl][2] + bb.z;
            float x3 = acc[tl][3] + bb.w;
            float s = x0 * x0 + x1 * x1 + x2 * x2 + x3 * x3;
            ssq[0] += (cbase < 40) ? s : 0.f;
            ssq[1] += (cbase >= 40 && cbase < 80) ? s : 0.f;
            ssq[2] += (cbase >= 80 && cbase < 120) ? s : 0.f;
            ssq[3] += (cbase >= 120) ? s : 0.f;
        }
#pragma unroll
        for (int c = 0; c < 4; ++c) {
            ssq[c] += __shfl_xor(ssq[c], 16);
            ssq[c] += __shfl_xor(ssq[c], 32);
        }
        float vq = (g == 0) ? ssq[0] : (g == 1) ? ssq[1] : (g == 2) ? ssq[2] : ssq[3];
        diffs[brow * 8 + (w & 1) * 4 + g] = sqrtf(vq);
    }

    // 4 quarter-phases: staging waves recompute acc+bb into Ostage; all stream
#pragma unroll
    for (int qq = 0; qq < 4; ++qq) {
        __syncthreads();
        if ((w >> 1) == qq) {
#pragma unroll
            for (int tl = 0; tl < 10; ++tl) {
                const int cbase = tl * 16 + g * 4;
                float4 bb = *(const float4*)&bp_b[wcol + cbase];
                f32x4 sv = {acc[tl][0] + bb.x, acc[tl][1] + bb.y,
                            acc[tl][2] + bb.z, acc[tl][3] + bb.w};
                *(f32x4*)&sm.b.Ostage[c16 * OSTRIDE + wcol + cbase] = sv;
            }
        }
        __syncthreads();
        float* dst = bias_p + (row0 + qq * 16) * HBD;
#pragma unroll
        for (int i = 0; i < 3; ++i) {
            const int f4 = t + i * 512;
            if (f4 < 1280) {
                const int fl = f4 * 4;
                const int r  = fl / 320;
                const int c  = fl - r * 320;
                f32x4 sv = *(const f32x4*)&sm.b.Ostage[r * OSTRIDE + c];
                *(f32x4*)&dst[fl] = sv;
            }
        }
    }
}

// ---------------------------------------------------------------------------
// attn via MFMA, flash-style, bf16 inputs (unchanged).
// ---------------------------------------------------------------------------
__global__ __launch_bounds__(256) void attn_mfma(const unsigned short* __restrict__ Qb,
                                                 const unsigned short* __restrict__ Kb,
                                                 const unsigned short* __restrict__ Vt,
                                                 const float* __restrict__ diffs,
                                                 float* __restrict__ vals)
{
    __shared__ float Lacc[4][64][17];
    __shared__ float Lm[4][16];
    __shared__ float Ll[4][16];

    const int t   = threadIdx.x;
    const int wv  = t >> 6;
    const int l   = t & 63;
    const int c16 = l & 15;
    const int g   = l >> 4;
    const int h   = blockIdx.y;
    const int n0  = blockIdx.x * 16;

    const unsigned short* qrow = Qb + (size_t)(n0 + c16) * DIM + h * HD;
    FragU Qf[2];
#pragma unroll
    for (int kh = 0; kh < 2; ++kh) {
        Qf[kh].d2[0] = *(const uint2*)(qrow + 4 * g + 32 * kh);
        Qf[kh].d2[1] = *(const uint2*)(qrow + 16 + 4 * g + 32 * kh);
    }

    float m_run = -1e30f, l_run = 0.f;
    f32x4 acc[4];
#pragma unroll
    for (int dt = 0; dt < 4; ++dt) acc[dt] = (f32x4){0.f, 0.f, 0.f, 0.f};

    for (int ti = 0; ti < 3; ++ti) {
        const int kb = (wv * 3 + ti) * 64;

        f32x4 s[4];
#pragma unroll
        for (int kt = 0; kt < 4; ++kt) s[kt] = (f32x4){0.f, 0.f, 0.f, 0.f};
#pragma unroll
        for (int kh = 0; kh < 2; ++kh) {
#pragma unroll
            for (int kt = 0; kt < 4; ++kt) {
                const unsigned short* krow = Kb + (size_t)(kb + kt * 16 + c16) * DIM + h * HD;
                FragU Kf;
                Kf.d2[0] = *(const uint2*)(krow + 4 * g + 32 * kh);
                Kf.d2[1] = *(const uint2*)(krow + 16 + 4 * g + 32 * kh);
                s[kt] = __builtin_amdgcn_mfma_f32_16x16x32_bf16(Kf.v, Qf[kh].v, s[kt], 0, 0, 0);
            }
        }

        const float* dbase = diffs + (size_t)h * 589824 + (size_t)(n0 + c16) * 768 + kb;
        float mx = -1e30f;
#pragma unroll
        for (int kt = 0; kt < 4; ++kt) {
            float4 d4 = *(const float4*)(dbase + kt * 16 + 4 * g);
            float dd[4] = {d4.x, d4.y, d4.z, d4.w};
#pragma unroll
            for (int r = 0; r < 4; ++r) {
                float x = s[kt][r] * 0.125f + dd[r];
                s[kt][r] = x;
                mx = fmaxf(mx, x);
            }
        }
        mx = fmaxf(mx, __shfl_xor(mx, 16));
        mx = fmaxf(mx, __shfl_xor(mx, 32));
        const float m_new = fmaxf(m_run, mx);
        const float scale = __expf(m_run - m_new);

        float psum = 0.f;
#pragma unroll
        for (int kt = 0; kt < 4; ++kt)
#pragma unroll
            for (int r = 0; r < 4; ++r) {
                float e = __expf(s[kt][r] - m_new);
                s[kt][r] = e;
                psum += e;
            }
        psum += __shfl_xor(psum, 16);
        psum += __shfl_xor(psum, 32);
        l_run = l_run * scale + psum;
        m_run = m_new;
#pragma unroll
        for (int dt = 0; dt < 4; ++dt)
#pragma unroll
            for (int r = 0; r < 4; ++r) acc[dt][r] *= scale;

        FragU Pf[2];
#pragma unroll
        for (int kh = 0; kh < 2; ++kh)
#pragma unroll
            for (int j = 0; j < 8; ++j)
                Pf[kh].u[j] = f2bf(s[2 * kh + (j >> 2)][j & 3]);

#pragma unroll
        for (int kh = 0; kh < 2; ++kh) {
#pragma unroll
            for (int dt = 0; dt < 4; ++dt) {
                const unsigned short* vrow =
                    Vt + (size_t)(h * HD + dt * 16 + c16) * NS + kb + 32 * kh + 4 * g;
                FragU Vf;
                Vf.d2[0] = *(const uint2*)(vrow);
                Vf.d2[1] = *(const uint2*)(vrow + 16);
                acc[dt] = __builtin_amdgcn_mfma_f32_16x16x32_bf16(Pf[kh].v, Vf.v, acc[dt], 0, 0, 0);
            }
        }
    }

#pragma unroll
    for (int dt = 0; dt < 4; ++dt)
#pragma unroll
        for (int r = 0; r < 4; ++r) Lacc[wv][l][dt * 4 + r] = acc[dt][r];
    if (g == 0) { Lm[wv][c16] = m_run; Ll[wv][c16] = l_run; }
    __syncthreads();

#pragma unroll
    for (int r = 0; r < 4; ++r) {
        const int qr = 4 * g + r;
        float M = fmaxf(fmaxf(Lm[0][qr], Lm[1][qr]), fmaxf(Lm[2][qr], Lm[3][qr]));
        float Lsum = 0.f, a = 0.f;
#pragma unroll
        for (int w2 = 0; w2 < 4; ++w2) {
            float e = __expf(Lm[w2][qr] - M);
            Lsum += Ll[w2][qr] * e;
            a += Lacc[w2][l][wv * 4 + r] * e;
        }
        vals[(size_t)(n0 + qr) * DIM + h * HD + wv * 16 + c16] = a / Lsum;
    }
}

// ---------------------------------------------------------------------------
extern "C" void kernel_launch(void* const* d_in, const int* in_sizes, int n_in,
                              void* d_out, int out_size, void* d_ws, size_t ws_size,
                              hipStream_t stream)
{
    const float* q    = (const float*)d_in[0];
    const float* k    = (const float*)d_in[1];
    const float* v    = (const float*)d_in[2];
    const float* bias = (const float*)d_in[3];
    const float* q_w  = (const float*)d_in[4];
    const float* q_b  = (const float*)d_in[5];
    const float* k_w  = (const float*)d_in[6];
    const float* k_b  = (const float*)d_in[7];
    const float* v_w  = (const float*)d_in[8];
    const float* v_b  = (const float*)d_in[9];
    const float* bp_w = (const float*)d_in[10];
    const float* bp_b = (const float*)d_in[11];
    const float* o1_w = (const float*)d_in[12];
    const float* o1_b = (const float*)d_in[13];
    const float* o2_w = (const float*)d_in[14];
    const float* o2_b = (const float*)d_in[15];

    float* out    = (float*)d_out;                 // [768][512]
    float* bias_p = (float*)d_out + 393216;        // [589824][320]

    float* ws    = (float*)d_ws;
    unsigned short* Qb = (unsigned short*)(ws);             // 768*512 bf16
    unsigned short* Kb = (unsigned short*)(ws + 393216);
    unsigned short* Vt = (unsigned short*)(ws + 786432);    // V^T [512][768] bf16
    float* vals  = ws + 1179648;
    float* mid   = ws + 1572864;
    float* diffs = ws + 1966080;       // 8*768*768

    dim3 gg(12, 8), gb(256);
    qkv_biasp<<<dim3(QKV_BLKS + NROWS / 64), dim3(512), 0, stream>>>(
        q, k, v, q_w, k_w, v_w, q_b, k_b, v_b, Qb, Kb, Vt,
        bias, bp_w, bp_b, bias_p, diffs);
    attn_mfma<<<dim3(48, NH), gb, 0, stream>>>(Qb, Kb, Vt, diffs, vals);
    gemm_mfma<<<gg, gb, 0, stream>>>(vals, o1_w, o1_b, mid, 3);
    gemm_mfma<<<gg, gb, 0, stream>>>(mid, o2_w, o2_b, out, 0);
}

// Round 17
// 259.666 us; speedup vs baseline: 1.0875x; 1.0875x over previous
//
#include <hip/hip_runtime.h>
#include <math.h>

#define NS   768
#define DIM  512
#define NH   8
#define HD   64
#define BD   40
#define HBD  320
#define NROWS (768*768)
#define OSTRIDE 321
#define QKV_BLKS 288

typedef __bf16 bf16x8 __attribute__((ext_vector_type(8)));
typedef float  f32x4  __attribute__((ext_vector_type(4)));

union FragU {
    bf16x8 v;
    unsigned short u[8];
    uint2 d2[2];
};

__device__ inline unsigned short f2bf(float f) {
    unsigned int u = __float_as_uint(f);
    unsigned int r = (u + 0x7fffu + ((u >> 16) & 1u)) >> 16;
    return (unsigned short)r;
}
__device__ inline unsigned int pk2(float x, float y) {
    return (unsigned)f2bf(x) | ((unsigned)f2bf(y) << 16);
}

// ---------------------------------------------------------------------------
// Standalone MFMA GEMM (256 thr). Used for o1 (mode 3) / o2 (mode 0).
// mode 0: f32 row-major   1: bf16 row-major   2: bf16 col-major   3: f32+mish
// ---------------------------------------------------------------------------
__global__ __launch_bounds__(256) void gemm_mfma(const float* __restrict__ A,
                                                 const float* __restrict__ W,
                                                 const float* __restrict__ bvec,
                                                 void* __restrict__ Cout,
                                                 int mode)
{
    __shared__ unsigned short As[64][72];
    __shared__ unsigned short Ws[64][72];

    const int t   = threadIdx.x;
    const int w   = t >> 6;
    const int l   = t & 63;
    const int c16 = l & 15;
    const int g   = l >> 4;
    const int m0  = blockIdx.x * 64;
    const int cb  = blockIdx.y * 64;

    f32x4 acc[4];
#pragma unroll
    for (int tl = 0; tl < 4; ++tl) acc[tl] = (f32x4){0.f, 0.f, 0.f, 0.f};

    for (int kc = 0; kc < DIM; kc += 64) {
        __syncthreads();
#pragma unroll
        for (int rep = 0; rep < 4; ++rep) {
            int f   = t + rep * 256;
            int row = f >> 4;
            int kk  = (f & 15) << 2;
            float4 a4 = *(const float4*)&A[(size_t)(m0 + row) * DIM + kc + kk];
            *(uint2*)&As[row][kk] = make_uint2(pk2(a4.x, a4.y), pk2(a4.z, a4.w));
            float4 w4 = *(const float4*)&W[(size_t)(cb + row) * DIM + kc + kk];
            *(uint2*)&Ws[row][kk] = make_uint2(pk2(w4.x, w4.y), pk2(w4.z, w4.w));
        }
        __syncthreads();
#pragma unroll
        for (int ks = 0; ks < 2; ++ks) {
            const int k0 = ks * 32;
            FragU bA;
            bA.d2[0] = *(const uint2*)&As[w * 16 + c16][k0 + 4 * g];
            bA.d2[1] = *(const uint2*)&As[w * 16 + c16][k0 + 16 + 4 * g];
#pragma unroll
            for (int tl = 0; tl < 4; ++tl) {
                FragU aW;
                aW.d2[0] = *(const uint2*)&Ws[tl * 16 + c16][k0 + 4 * g];
                aW.d2[1] = *(const uint2*)&Ws[tl * 16 + c16][k0 + 16 + 4 * g];
                acc[tl] = __builtin_amdgcn_mfma_f32_16x16x32_bf16(aW.v, bA.v, acc[tl], 0, 0, 0);
            }
        }
    }

    const int row = m0 + w * 16 + c16;
#pragma unroll
    for (int tl = 0; tl < 4; ++tl) {
        const int col = cb + tl * 16 + g * 4;
        float4 bb = *(const float4*)&bvec[col];
        float o[4] = {acc[tl][0] + bb.x, acc[tl][1] + bb.y,
                      acc[tl][2] + bb.z, acc[tl][3] + bb.w};
        if (mode == 3) {
#pragma unroll
            for (int rr = 0; rr < 4; ++rr)
                o[rr] = o[rr] * tanhf(log1pf(expf(o[rr])));
        }
        if (mode == 0 || mode == 3) {
            *(float4*)&((float*)Cout)[(size_t)row * DIM + col] =
                make_float4(o[0], o[1], o[2], o[3]);
        } else if (mode == 1) {
            *(uint2*)&((unsigned short*)Cout)[(size_t)row * DIM + col] =
                make_uint2(pk2(o[0], o[1]), pk2(o[2], o[3]));
        } else {
            unsigned short* p = (unsigned short*)Cout;
#pragma unroll
            for (int rr = 0; rr < 4; ++rr)
                p[(size_t)(col + rr) * NS + row] = f2bf(o[rr]);
        }
    }
}

// ---------------------------------------------------------------------------
// Fused QKV + biasp, 512 threads, heterogeneous grid:
//   blocks [0, 288): QKV projection gemms (which = b/96), 64x64 tile, 8 waves
//   blocks [288, 9504): biasp (MFMA + 32-row LDS-restage linear stores)
// ---------------------------------------------------------------------------
struct SMemG { unsigned short As[64][72]; unsigned short Ws[64][72]; };
struct SMemB { unsigned short Wl[HBD * BD]; float Ostage[32 * OSTRIDE]; };
union SMemU { SMemG g; SMemB b; };

__global__ __launch_bounds__(512) void qkv_biasp(
    const float* __restrict__ q, const float* __restrict__ k, const float* __restrict__ v,
    const float* __restrict__ q_w, const float* __restrict__ k_w, const float* __restrict__ v_w,
    const float* __restrict__ q_b, const float* __restrict__ k_b, const float* __restrict__ v_b,
    unsigned short* __restrict__ Qb, unsigned short* __restrict__ Kb, unsigned short* __restrict__ Vt,
    const float* __restrict__ bias, const float* __restrict__ bp_w, const float* __restrict__ bp_b,
    float* __restrict__ bias_p, float* __restrict__ diffs)
{
    __shared__ SMemU sm;

    const int t   = threadIdx.x;
    const int wv  = t >> 6;
    const int l   = t & 63;
    const int c16 = l & 15;
    const int g   = l >> 4;

    if (blockIdx.x < QKV_BLKS) {
        // ================= QKV gemm path =================
        const int sub   = blockIdx.x;
        const int which = sub / 96;            // 0=Q 1=K 2=V
        const int rem   = sub - which * 96;
        const int m0    = (rem % 12) * 64;
        const int cb    = (rem / 12) * 64;
        const float* A  = (which == 0) ? q   : (which == 1) ? k   : v;
        const float* W  = (which == 0) ? q_w : (which == 1) ? k_w : v_w;
        const float* Bv = (which == 0) ? q_b : (which == 1) ? k_b : v_b;

        const int wr = wv >> 1;               // 0..3 row-group
        const int wc = wv & 1;                // 0..1 col-group

        f32x4 acc[2];
        acc[0] = (f32x4){0.f, 0.f, 0.f, 0.f};
        acc[1] = (f32x4){0.f, 0.f, 0.f, 0.f};

        for (int kc = 0; kc < DIM; kc += 64) {
            __syncthreads();
#pragma unroll
            for (int rep = 0; rep < 2; ++rep) {
                int f   = t + rep * 512;
                int row = f >> 4;
                int kk  = (f & 15) << 2;
                float4 a4 = *(const float4*)&A[(size_t)(m0 + row) * DIM + kc + kk];
                *(uint2*)&sm.g.As[row][kk] = make_uint2(pk2(a4.x, a4.y), pk2(a4.z, a4.w));
                float4 w4 = *(const float4*)&W[(size_t)(cb + row) * DIM + kc + kk];
                *(uint2*)&sm.g.Ws[row][kk] = make_uint2(pk2(w4.x, w4.y), pk2(w4.z, w4.w));
            }
            __syncthreads();
#pragma unroll
            for (int ks = 0; ks < 2; ++ks) {
                const int k0 = ks * 32;
                FragU bA;
                bA.d2[0] = *(const uint2*)&sm.g.As[wr * 16 + c16][k0 + 4 * g];
                bA.d2[1] = *(const uint2*)&sm.g.As[wr * 16 + c16][k0 + 16 + 4 * g];
#pragma unroll
                for (int tl = 0; tl < 2; ++tl) {
                    FragU aW;
                    aW.d2[0] = *(const uint2*)&sm.g.Ws[wc * 32 + tl * 16 + c16][k0 + 4 * g];
                    aW.d2[1] = *(const uint2*)&sm.g.Ws[wc * 32 + tl * 16 + c16][k0 + 16 + 4 * g];
                    acc[tl] = __builtin_amdgcn_mfma_f32_16x16x32_bf16(aW.v, bA.v, acc[tl], 0, 0, 0);
                }
            }
        }

        const int row = m0 + wr * 16 + c16;
#pragma unroll
        for (int tl = 0; tl < 2; ++tl) {
            const int col = cb + wc * 32 + tl * 16 + g * 4;
            float4 bb = *(const float4*)&Bv[col];
            float o0 = acc[tl][0] + bb.x;
            float o1 = acc[tl][1] + bb.y;
            float o2 = acc[tl][2] + bb.z;
            float o3 = acc[tl][3] + bb.w;
            if (which < 2) {
                unsigned short* p = (which == 0) ? Qb : Kb;
                *(uint2*)&p[(size_t)row * DIM + col] =
                    make_uint2(pk2(o0, o1), pk2(o2, o3));
            } else {
                Vt[(size_t)(col + 0) * NS + row] = f2bf(o0);
                Vt[(size_t)(col + 1) * NS + row] = f2bf(o1);
                Vt[(size_t)(col + 2) * NS + row] = f2bf(o2);
                Vt[(size_t)(col + 3) * NS + row] = f2bf(o3);
            }
        }
        return;
    }

    // ================= biasp path (r10/r14) =================
    const long row0 = (long)(blockIdx.x - QKV_BLKS) * 64;
    const int  w    = wv;
    const int  wrow = (w >> 1) * 16;
    const int  wcol = (w & 1) * 160;

    const long arow = row0 + wrow + c16;
    const float* ap = bias + arow * BD;
    float4 a0 = *(const float4*)(ap + g * 4);
    float4 a1 = *(const float4*)(ap + 16 + g * 4);
    float4 a2 = make_float4(0.f, 0.f, 0.f, 0.f);
    if (g < 2) a2 = *(const float4*)(ap + 32 + g * 4);

    for (int i = t; i < HBD * BD / 4; i += 512) {
        float4 w4 = ((const float4*)bp_w)[i];
        ((uint2*)sm.b.Wl)[i] = make_uint2(pk2(w4.x, w4.y), pk2(w4.z, w4.w));
    }

    FragU A0, A1;
    A0.d2[0] = make_uint2(pk2(a0.x, a0.y), pk2(a0.z, a0.w));
    A0.d2[1] = make_uint2(pk2(a1.x, a1.y), pk2(a1.z, a1.w));
    A1.d2[0] = make_uint2(pk2(a2.x, a2.y), pk2(a2.z, a2.w));
    A1.d2[1] = make_uint2(0u, 0u);

    __syncthreads();

    f32x4 acc[10];
#pragma unroll
    for (int tl = 0; tl < 10; ++tl) acc[tl] = (f32x4){0.f, 0.f, 0.f, 0.f};

#pragma unroll
    for (int tl = 0; tl < 10; ++tl) {
        const int n = wcol + tl * 16 + c16;
        const uint2* wp = (const uint2*)(sm.b.Wl + n * BD);
        FragU B0, B1;
        B0.d2[0] = wp[g];
        B0.d2[1] = wp[4 + g];
        B1.d2[0] = (g < 2) ? wp[8 + g] : make_uint2(0u, 0u);
        B1.d2[1] = make_uint2(0u, 0u);
        acc[tl] = __builtin_amdgcn_mfma_f32_16x16x32_bf16(B0.v, A0.v, acc[tl], 0, 0, 0);
        acc[tl] = __builtin_amdgcn_mfma_f32_16x16x32_bf16(B1.v, A1.v, acc[tl], 0, 0, 0);
    }

#pragma unroll
    for (int half = 0; half < 2; ++half) {
        __syncthreads();
        if ((wrow >> 5) == half) {
            const int lrow = (wrow & 31) + c16;
            const long brow = row0 + wrow + c16;
            float ssq[4] = {0.f, 0.f, 0.f, 0.f};
#pragma unroll
            for (int tl = 0; tl < 10; ++tl) {
                const int cbase = tl * 16 + g * 4;
                float4 bb = *(const float4*)&bp_b[wcol + cbase];
                float x0 = acc[tl][0] + bb.x;
                float x1 = acc[tl][1] + bb.y;
                float x2 = acc[tl][2] + bb.z;
                float x3 = acc[tl][3] + bb.w;
                f32x4 sv = {x0, x1, x2, x3};
                *(f32x4*)&sm.b.Ostage[lrow * OSTRIDE + wcol + cbase] = sv;
                float s = x0 * x0 + x1 * x1 + x2 * x2 + x3 * x3;
                ssq[0] += (cbase < 40) ? s : 0.f;
                ssq[1] += (cbase >= 40 && cbase < 80) ? s : 0.f;
                ssq[2] += (cbase >= 80 && cbase < 120) ? s : 0.f;
                ssq[3] += (cbase >= 120) ? s : 0.f;
            }
#pragma unroll
            for (int c = 0; c < 4; ++c) {
                ssq[c] += __shfl_xor(ssq[c], 16);
                ssq[c] += __shfl_xor(ssq[c], 32);
            }
            float vq = (g == 0) ? ssq[0] : (g == 1) ? ssq[1] : (g == 2) ? ssq[2] : ssq[3];
            diffs[brow * 8 + (w & 1) * 4 + g] = sqrtf(vq);
        }
        __syncthreads();
        float* dst = bias_p + (row0 + half * 32) * HBD;
#pragma unroll
        for (int i = 0; i < 5; ++i) {
            const int f4 = t + i * 512;
            const int fl = f4 * 4;
            const int r  = fl / 320;
            const int c  = fl - r * 320;
            f32x4 sv = *(const f32x4*)&sm.b.Ostage[r * OSTRIDE + c];
            *(f32x4*)&dst[fl] = sv;
        }
    }
}

// ---------------------------------------------------------------------------
// attn via MFMA, flash-style, bf16 inputs.
// ---------------------------------------------------------------------------
__global__ __launch_bounds__(256) void attn_mfma(const unsigned short* __restrict__ Qb,
                                                 const unsigned short* __restrict__ Kb,
                                                 const unsigned short* __restrict__ Vt,
                                                 const float* __restrict__ diffs,
                                                 float* __restrict__ vals)
{
    __shared__ float Lacc[4][64][17];
    __shared__ float Lm[4][16];
    __shared__ float Ll[4][16];

    const int t   = threadIdx.x;
    const int wv  = t >> 6;
    const int l   = t & 63;
    const int c16 = l & 15;
    const int g   = l >> 4;
    const int h   = blockIdx.y;
    const int n0  = blockIdx.x * 16;

    const unsigned short* qrow = Qb + (size_t)(n0 + c16) * DIM + h * HD;
    FragU Qf[2];
#pragma unroll
    for (int kh = 0; kh < 2; ++kh) {
        Qf[kh].d2[0] = *(const uint2*)(qrow + 4 * g + 32 * kh);
        Qf[kh].d2[1] = *(const uint2*)(qrow + 16 + 4 * g + 32 * kh);
    }

    float m_run = -1e30f, l_run = 0.f;
    f32x4 acc[4];
#pragma unroll
    for (int dt = 0; dt < 4; ++dt) acc[dt] = (f32x4){0.f, 0.f, 0.f, 0.f};

    for (int ti = 0; ti < 3; ++ti) {
        const int kb = (wv * 3 + ti) * 64;

        f32x4 s[4];
#pragma unroll
        for (int kt = 0; kt < 4; ++kt) s[kt] = (f32x4){0.f, 0.f, 0.f, 0.f};
#pragma unroll
        for (int kh = 0; kh < 2; ++kh) {
#pragma unroll
            for (int kt = 0; kt < 4; ++kt) {
                const unsigned short* krow = Kb + (size_t)(kb + kt * 16 + c16) * DIM + h * HD;
                FragU Kf;
                Kf.d2[0] = *(const uint2*)(krow + 4 * g + 32 * kh);
                Kf.d2[1] = *(const uint2*)(krow + 16 + 4 * g + 32 * kh);
                s[kt] = __builtin_amdgcn_mfma_f32_16x16x32_bf16(Kf.v, Qf[kh].v, s[kt], 0, 0, 0);
            }
        }

        const float* dbase = diffs + (size_t)h * 589824 + (size_t)(n0 + c16) * 768 + kb;
        float mx = -1e30f;
#pragma unroll
        for (int kt = 0; kt < 4; ++kt) {
            float4 d4 = *(const float4*)(dbase + kt * 16 + 4 * g);
            float dd[4] = {d4.x, d4.y, d4.z, d4.w};
#pragma unroll
            for (int r = 0; r < 4; ++r) {
                float x = s[kt][r] * 0.125f + dd[r];
                s[kt][r] = x;
                mx = fmaxf(mx, x);
            }
        }
        mx = fmaxf(mx, __shfl_xor(mx, 16));
        mx = fmaxf(mx, __shfl_xor(mx, 32));
        const float m_new = fmaxf(m_run, mx);
        const float scale = __expf(m_run - m_new);

        float psum = 0.f;
#pragma unroll
        for (int kt = 0; kt < 4; ++kt)
#pragma unroll
            for (int r = 0; r < 4; ++r) {
                float e = __expf(s[kt][r] - m_new);
                s[kt][r] = e;
                psum += e;
            }
        psum += __shfl_xor(psum, 16);
        psum += __shfl_xor(psum, 32);
        l_run = l_run * scale + psum;
        m_run = m_new;
#pragma unroll
        for (int dt = 0; dt < 4; ++dt)
#pragma unroll
            for (int r = 0; r < 4; ++r) acc[dt][r] *= scale;

        FragU Pf[2];
#pragma unroll
        for (int kh = 0; kh < 2; ++kh)
#pragma unroll
            for (int j = 0; j < 8; ++j)
                Pf[kh].u[j] = f2bf(s[2 * kh + (j >> 2)][j & 3]);

#pragma unroll
        for (int kh = 0; kh < 2; ++kh) {
#pragma unroll
            for (int dt = 0; dt < 4; ++dt) {
                const unsigned short* vrow =
                    Vt + (size_t)(h * HD + dt * 16 + c16) * NS + kb + 32 * kh + 4 * g;
                FragU Vf;
                Vf.d2[0] = *(const uint2*)(vrow);
                Vf.d2[1] = *(const uint2*)(vrow + 16);
                acc[dt] = __builtin_amdgcn_mfma_f32_16x16x32_bf16(Pf[kh].v, Vf.v, acc[dt], 0, 0, 0);
            }
        }
    }

#pragma unroll
    for (int dt = 0; dt < 4; ++dt)
#pragma unroll
        for (int r = 0; r < 4; ++r) Lacc[wv][l][dt * 4 + r] = acc[dt][r];
    if (g == 0) { Lm[wv][c16] = m_run; Ll[wv][c16] = l_run; }
    __syncthreads();

#pragma unroll
    for (int r = 0; r < 4; ++r) {
        const int qr = 4 * g + r;
        float M = fmaxf(fmaxf(Lm[0][qr], Lm[1][qr]), fmaxf(Lm[2][qr], Lm[3][qr]));
        float Lsum = 0.f, a = 0.f;
#pragma unroll
        for (int w2 = 0; w2 < 4; ++w2) {
            float e = __expf(Lm[w2][qr] - M);
            Lsum += Ll[w2][qr] * e;
            a += Lacc[w2][l][wv * 4 + r] * e;
        }
        vals[(size_t)(n0 + qr) * DIM + h * HD + wv * 16 + c16] = a / Lsum;
    }
}

// ---------------------------------------------------------------------------
extern "C" void kernel_launch(void* const* d_in, const int* in_sizes, int n_in,
                              void* d_out, int out_size, void* d_ws, size_t ws_size,
                              hipStream_t stream)
{
    const float* q    = (const float*)d_in[0];
    const float* k    = (const float*)d_in[1];
    const float* v    = (const float*)d_in[2];
    const float* bias = (const float*)d_in[3];
    const float* q_w  = (const float*)d_in[4];
    const float* q_b  = (const float*)d_in[5];
    const float* k_w  = (const float*)d_in[6];
    const float* k_b  = (const float*)d_in[7];
    const float* v_w  = (const float*)d_in[8];
    const float* v_b  = (const float*)d_in[9];
    const float* bp_w = (const float*)d_in[10];
    const float* bp_b = (const float*)d_in[11];
    const float* o1_w = (const float*)d_in[12];
    const float* o1_b = (const float*)d_in[13];
    const float* o2_w = (const float*)d_in[14];
    const float* o2_b = (const float*)d_in[15];

    float* out    = (float*)d_out;                 // [768][512]
    float* bias_p = (float*)d_out + 393216;        // [589824][320]

    float* ws    = (float*)d_ws;
    unsigned short* Qb = (unsigned short*)(ws);             // 768*512 bf16
    unsigned short* Kb = (unsigned short*)(ws + 393216);
    unsigned short* Vt = (unsigned short*)(ws + 786432);    // V^T [512][768] bf16
    float* vals  = ws + 1179648;
    float* mid   = ws + 1572864;
    float* diffs = ws + 1966080;       // 8*768*768

    dim3 gg(12, 8), gb(256);
    qkv_biasp<<<dim3(QKV_BLKS + NROWS / 64), dim3(512), 0, stream>>>(
        q, k, v, q_w, k_w, v_w, q_b, k_b, v_b, Qb, Kb, Vt,
        bias, bp_w, bp_b, bias_p, diffs);
    attn_mfma<<<dim3(48, NH), gb, 0, stream>>>(Qb, Kb, Vt, diffs, vals);
    gemm_mfma<<<gg, gb, 0, stream>>>(vals, o1_w, o1_b, mid, 3);
    gemm_mfma<<<gg, gb, 0, stream>>>(mid, o2_w, o2_b, out, 0);
}